// Round 6
// baseline (367.546 us; speedup 1.0000x reference)
//
#include <hip/hip_runtime.h>

#define NEG 0.2f

constexpr int SCAN_BLOCKS = 64;

// ===========================================================================
// Phase A: build dst-sorted CSR (shared by both GAT layers)
// ===========================================================================
__global__ void hist_kernel(const int* __restrict__ ei, int* __restrict__ counts, int E)
{
  const int i = blockIdx.x * 256 + threadIdx.x;
  if (i < E) atomicAdd(&counts[ei[E + i]], 1);
}

__global__ __launch_bounds__(256) void scan_a(const int* __restrict__ counts,
                                              int* __restrict__ partial, int N)
{
  const int b = blockIdx.x, t = threadIdx.x;
  const int per_block = (N + SCAN_BLOCKS - 1) / SCAN_BLOCKS;
  const int beg = b * per_block;
  const int end = min(beg + per_block, N);
  int s = 0;
  for (int i = beg + t; i < end; i += 256) s += counts[i];
#pragma unroll
  for (int m = 32; m >= 1; m >>= 1) s += __shfl_xor(s, m, 64);
  __shared__ int ws[4];
  if ((t & 63) == 0) ws[t >> 6] = s;
  __syncthreads();
  if (t == 0) partial[b] = ws[0] + ws[1] + ws[2] + ws[3];
}

__global__ __launch_bounds__(256) void scan_c(const int* __restrict__ counts,
                                              const int* __restrict__ partial,
                                              int* __restrict__ offs,
                                              int* __restrict__ cursor, int N)
{
  const int b = blockIdx.x, t = threadIdx.x;
  const int per_block = (N + SCAN_BLOCKS - 1) / SCAN_BLOCKS;
  const int per_thread = (per_block + 255) / 256;
  const int beg = b * per_block;
  const int end = min(beg + per_block, N);

  int base = 0;
  for (int i = 0; i < SCAN_BLOCKS; ++i)
    if (i < b) base += partial[i];

  const int tbeg = beg + t * per_thread;
  const int tend = min(tbeg + per_thread, end);
  int tsum = 0;
  for (int i = tbeg; i < tend; ++i) tsum += counts[i];

  __shared__ int sums[256];
  sums[t] = tsum;
  __syncthreads();
  for (int off = 1; off < 256; off <<= 1) {
    int v = (t >= off) ? sums[t - off] : 0;
    __syncthreads();
    if (t >= off) sums[t] += v;
    __syncthreads();
  }
  int run = base + (t ? sums[t - 1] : 0);
  for (int i = tbeg; i < tend; ++i) {
    offs[i] = run;
    cursor[i] = run;
    run += counts[i];
  }
  if (b == SCAN_BLOCKS - 1 && t == 255) offs[N] = base + sums[255];
}

__global__ void scatter_kernel(const int* __restrict__ ei, int* __restrict__ cursor,
                               int* __restrict__ ssrc, int* __restrict__ sdst, int E)
{
  const int i = blockIdx.x * 256 + threadIdx.x;
  if (i < E) {
    const int d = ei[E + i];
    const int pos = atomicAdd(&cursor[d], 1);
    ssrc[pos] = ei[i];
    sdst[pos] = d;
  }
}

// ===========================================================================
// Edge-parallel softmax-weight precompute
// ===========================================================================
__global__ void edgew1_kernel(const int* __restrict__ ssrc, const int* __restrict__ sdst,
                              const float* __restrict__ asrc, const float* __restrict__ adst,
                              float2* __restrict__ ew, int E)
{
  const int i = blockIdx.x * 256 + threadIdx.x;
  if (i >= E) return;
  const int s = ssrc[i], d = sdst[i];
  const float2 av = *(const float2*)(asrc + 2 * s);
  const float2 dv = *(const float2*)(adst + 2 * d);
  float e0 = av.x + dv.x, e1 = av.y + dv.y;
  e0 = e0 > 0.f ? e0 : NEG * e0;
  e1 = e1 > 0.f ? e1 : NEG * e1;
  ew[i] = make_float2(__expf(e0), __expf(e1));
}

__global__ void edgew2_kernel(const int* __restrict__ ssrc, const int* __restrict__ sdst,
                              const float* __restrict__ asrc, const float* __restrict__ adst,
                              float* __restrict__ ew, int E)
{
  const int i = blockIdx.x * 256 + threadIdx.x;
  if (i >= E) return;
  float e = asrc[ssrc[i]] + adst[sdst[i]];
  e = e > 0.f ? e : NEG * e;
  ew[i] = __expf(e);
}

// ===========================================================================
// GEMM1: h1 = x @ W1  (N x 128)@(128 x 128). LDS-tiled: BM=32 nodes/block,
// 256 thr, thread = 4 nodes x 4 cols. Fused alpha_src/alpha_dst epilogue.
// ===========================================================================
constexpr int BM1 = 32;

__global__ __launch_bounds__(256) void gemm1_kernel(
    const float* __restrict__ x, const float* __restrict__ W,
    const float* __restrict__ a_src, const float* __restrict__ a_dst,
    float* __restrict__ h, float* __restrict__ asrc, float* __restrict__ adst,
    int N)
{
  __shared__ float xs[BM1][132];   // +4 pad: conflict-free b128 reads
  const int t = threadIdx.x;
  const int n0 = blockIdx.x * BM1;

  // stage x tile (32x128 fp32, coalesced float4)
#pragma unroll
  for (int i = 0; i < 4; ++i) {
    const int idx = t + i * 256;       // float4 slot 0..1023
    const int row = idx >> 5;
    const int cq  = idx & 31;
    int rn = n0 + row; if (rn >= N) rn = N - 1;
    *(float4*)&xs[row][cq * 4] = *(const float4*)(x + (size_t)rn * 128 + cq * 4);
  }
  __syncthreads();

  const int c4 = (t & 31) << 2;        // cols c4..c4+3
  const int tn = (t >> 5) << 2;        // first of 4 local nodes

  float4 acc[4];
#pragma unroll
  for (int j = 0; j < 4; ++j) acc[j] = make_float4(0.f, 0.f, 0.f, 0.f);

  for (int k0 = 0; k0 < 128; k0 += 4) {
    const float4 w0 = *(const float4*)(W + (k0 + 0) * 128 + c4);
    const float4 w1 = *(const float4*)(W + (k0 + 1) * 128 + c4);
    const float4 w2 = *(const float4*)(W + (k0 + 2) * 128 + c4);
    const float4 w3 = *(const float4*)(W + (k0 + 3) * 128 + c4);
#pragma unroll
    for (int j = 0; j < 4; ++j) {
      const float4 xv = *(const float4*)&xs[tn + j][k0];
      acc[j].x += xv.x * w0.x + xv.y * w1.x + xv.z * w2.x + xv.w * w3.x;
      acc[j].y += xv.x * w0.y + xv.y * w1.y + xv.z * w2.y + xv.w * w3.y;
      acc[j].z += xv.x * w0.z + xv.y * w1.z + xv.z * w2.z + xv.w * w3.z;
      acc[j].w += xv.x * w0.w + xv.y * w1.w + xv.z * w2.w + xv.w * w3.w;
    }
  }

  const float4 avs = *(const float4*)(a_src + c4);
  const float4 avd = *(const float4*)(a_dst + c4);
  const int head = (t >> 4) & 1;

#pragma unroll
  for (int j = 0; j < 4; ++j) {
    const int nn = n0 + tn + j;
    if (nn >= N) break;
    *(float4*)(h + (size_t)nn * 128 + c4) = acc[j];
    float vs = acc[j].x * avs.x + acc[j].y * avs.y + acc[j].z * avs.z + acc[j].w * avs.w;
    float vd = acc[j].x * avd.x + acc[j].y * avd.y + acc[j].z * avd.z + acc[j].w * avd.w;
#pragma unroll
    for (int m = 1; m <= 8; m <<= 1) {
      vs += __shfl_xor(vs, m, 64);
      vd += __shfl_xor(vd, m, 64);
    }
    if ((t & 15) == 0) {
      asrc[nn * 2 + head] = vs;
      adst[nn * 2 + head] = vd;
    }
  }
}

// ===========================================================================
// GEMM2: h2 = out1 @ W2  (N x 128)@(128 x 32). LDS-tiled: BM=64 nodes/block,
// 256 thr, thread = 2 nodes x 4 cols. Fused alpha2 epilogue (single head).
// ===========================================================================
constexpr int BM2 = 64;

__global__ __launch_bounds__(256) void gemm2_kernel(
    const float* __restrict__ x, const float* __restrict__ W,
    const float* __restrict__ a_src, const float* __restrict__ a_dst,
    float* __restrict__ h, float* __restrict__ asrc, float* __restrict__ adst,
    int N)
{
  __shared__ float xs[BM2][132];
  const int t = threadIdx.x;
  const int n0 = blockIdx.x * BM2;

#pragma unroll
  for (int i = 0; i < 8; ++i) {
    const int idx = t + i * 256;       // float4 slot 0..2047
    const int row = idx >> 5;
    const int cq  = idx & 31;
    int rn = n0 + row; if (rn >= N) rn = N - 1;
    *(float4*)&xs[row][cq * 4] = *(const float4*)(x + (size_t)rn * 128 + cq * 4);
  }
  __syncthreads();

  const int c4 = (t & 7) << 2;         // cols c4..c4+3 (of 32)
  const int tn = (t >> 3) << 1;        // first of 2 local nodes

  float4 acc[2];
#pragma unroll
  for (int j = 0; j < 2; ++j) acc[j] = make_float4(0.f, 0.f, 0.f, 0.f);

  for (int k0 = 0; k0 < 128; k0 += 4) {
    const float4 w0 = *(const float4*)(W + (k0 + 0) * 32 + c4);
    const float4 w1 = *(const float4*)(W + (k0 + 1) * 32 + c4);
    const float4 w2 = *(const float4*)(W + (k0 + 2) * 32 + c4);
    const float4 w3 = *(const float4*)(W + (k0 + 3) * 32 + c4);
#pragma unroll
    for (int j = 0; j < 2; ++j) {
      const float4 xv = *(const float4*)&xs[tn + j][k0];
      acc[j].x += xv.x * w0.x + xv.y * w1.x + xv.z * w2.x + xv.w * w3.x;
      acc[j].y += xv.x * w0.y + xv.y * w1.y + xv.z * w2.y + xv.w * w3.y;
      acc[j].z += xv.x * w0.z + xv.y * w1.z + xv.z * w2.z + xv.w * w3.z;
      acc[j].w += xv.x * w0.w + xv.y * w1.w + xv.z * w2.w + xv.w * w3.w;
    }
  }

  const float4 avs = *(const float4*)(a_src + c4);
  const float4 avd = *(const float4*)(a_dst + c4);

#pragma unroll
  for (int j = 0; j < 2; ++j) {
    const int nn = n0 + tn + j;
    if (nn >= N) break;
    *(float4*)(h + (size_t)nn * 32 + c4) = acc[j];
    float vs = acc[j].x * avs.x + acc[j].y * avs.y + acc[j].z * avs.z + acc[j].w * avs.w;
    float vd = acc[j].x * avd.x + acc[j].y * avd.y + acc[j].z * avd.z + acc[j].w * avd.w;
#pragma unroll
    for (int m = 1; m <= 4; m <<= 1) {
      vs += __shfl_xor(vs, m, 64);
      vd += __shfl_xor(vd, m, 64);
    }
    if ((t & 7) == 0) {
      asrc[nn] = vs;
      adst[nn] = vd;
    }
  }
}

// ===========================================================================
// Layer-1 segment aggregation (unchanged from round 4)
// ===========================================================================
__global__ __launch_bounds__(256) void agg1_kernel(
    const int* __restrict__ offs, const int* __restrict__ ssrc,
    const float2* __restrict__ ew,
    const float* __restrict__ h, const float* __restrict__ asrc,
    const float* __restrict__ adst, const float* __restrict__ b,
    float* __restrict__ out, int N)
{
  const int n = (blockIdx.x * 256 + threadIdx.x) >> 6;
  const int lane = threadIdx.x & 63;
  const int c = lane & 31;
  const int half = lane >> 5;
  const int head = c >> 4;
  if (n >= N) return;

  float4 a = make_float4(0.f, 0.f, 0.f, 0.f);
  float den = 0.f;

  const int beg = offs[n];
  const int end = offs[n + 1];

  for (int i0 = beg + half; i0 < end; i0 += 8) {
    const int i1 = i0 + 2, i2 = i0 + 4, i3 = i0 + 6;
    const bool v1 = i1 < end, v2 = i2 < end, v3 = i3 < end;

    const int s0 = ssrc[i0];
    const int s1 = v1 ? ssrc[i1] : s0;
    const int s2 = v2 ? ssrc[i2] : s0;
    const int s3 = v3 ? ssrc[i3] : s0;

    const float2 ww0 = ew[i0];
    const float2 ww1 = v1 ? ew[i1] : make_float2(0.f, 0.f);
    const float2 ww2 = v2 ? ew[i2] : make_float2(0.f, 0.f);
    const float2 ww3 = v3 ? ew[i3] : make_float2(0.f, 0.f);

    const float4 h0 = *(const float4*)(h + (size_t)s0 * 128 + c * 4);
    const float4 h1 = *(const float4*)(h + (size_t)s1 * 128 + c * 4);
    const float4 h2 = *(const float4*)(h + (size_t)s2 * 128 + c * 4);
    const float4 h3 = *(const float4*)(h + (size_t)s3 * 128 + c * 4);

    const float w0 = head ? ww0.y : ww0.x;
    const float w1 = head ? ww1.y : ww1.x;
    const float w2 = head ? ww2.y : ww2.x;
    const float w3 = head ? ww3.y : ww3.x;

    den += (w0 + w1) + (w2 + w3);
    a.x += w0 * h0.x + w1 * h1.x + w2 * h2.x + w3 * h3.x;
    a.y += w0 * h0.y + w1 * h1.y + w2 * h2.y + w3 * h3.y;
    a.z += w0 * h0.z + w1 * h1.z + w2 * h2.z + w3 * h3.z;
    a.w += w0 * h0.w + w1 * h1.w + w2 * h2.w + w3 * h3.w;
  }

  if (half == 0) {  // self-loop
    const float2 asv = *(const float2*)(asrc + 2 * n);
    const float2 adv = *(const float2*)(adst + 2 * n);
    float e = head ? (asv.y + adv.y) : (asv.x + adv.x);
    e = e > 0.f ? e : NEG * e;
    const float w = __expf(e);
    den += w;
    const float4 hv = *(const float4*)(h + (size_t)n * 128 + c * 4);
    a.x += w * hv.x; a.y += w * hv.y; a.z += w * hv.z; a.w += w * hv.w;
  }

  a.x += __shfl_xor(a.x, 32, 64);
  a.y += __shfl_xor(a.y, 32, 64);
  a.z += __shfl_xor(a.z, 32, 64);
  a.w += __shfl_xor(a.w, 32, 64);
  den += __shfl_xor(den, 32, 64);

  if (half == 0) {
    const float4 bv = *(const float4*)(b + c * 4);
    const float inv = 1.f / den;
    float4 r;
    r.x = a.x * inv + bv.x;
    r.y = a.y * inv + bv.y;
    r.z = a.z * inv + bv.z;
    r.w = a.w * inv + bv.w;
    r.x = r.x > 0.f ? r.x : 0.f;
    r.y = r.y > 0.f ? r.y : 0.f;
    r.z = r.z > 0.f ? r.z : 0.f;
    r.w = r.w > 0.f ? r.w : 0.f;
    *(float4*)(out + (size_t)n * 128 + c * 4) = r;
  }
}

// ===========================================================================
// Layer-2 segment aggregation (unchanged from round 4)
// ===========================================================================
__global__ __launch_bounds__(256) void agg2_kernel(
    const int* __restrict__ offs, const int* __restrict__ ssrc,
    const float* __restrict__ ew,
    const float* __restrict__ h, const float* __restrict__ asrc,
    const float* __restrict__ adst, const float* __restrict__ b,
    float* __restrict__ out, int N)
{
  const int n = (blockIdx.x * 256 + threadIdx.x) >> 6;
  const int lane = threadIdx.x & 63;
  const int g = lane >> 3;
  const int c4 = (lane & 7) << 2;
  if (n >= N) return;

  float4 a = make_float4(0.f, 0.f, 0.f, 0.f);
  float den = 0.f;

  const int beg = offs[n];
  const int end = offs[n + 1];

  for (int i0 = beg + g; i0 < end; i0 += 16) {
    const int i1 = i0 + 8;
    const bool v1 = i1 < end;

    const int s0 = ssrc[i0];
    const int s1 = v1 ? ssrc[i1] : s0;
    const float w0 = ew[i0];
    const float w1 = v1 ? ew[i1] : 0.f;

    const float4 h0 = *(const float4*)(h + (size_t)s0 * 32 + c4);
    const float4 h1 = *(const float4*)(h + (size_t)s1 * 32 + c4);

    den += w0 + w1;
    a.x += w0 * h0.x + w1 * h1.x;
    a.y += w0 * h0.y + w1 * h1.y;
    a.z += w0 * h0.z + w1 * h1.z;
    a.w += w0 * h0.w + w1 * h1.w;
  }

  if (g == 0) {  // self-loop
    float e = asrc[n] + adst[n];
    e = e > 0.f ? e : NEG * e;
    const float w = __expf(e);
    den += w;
    const float4 hv = *(const float4*)(h + (size_t)n * 32 + c4);
    a.x += w * hv.x; a.y += w * hv.y; a.z += w * hv.z; a.w += w * hv.w;
  }

#pragma unroll
  for (int m = 8; m <= 32; m <<= 1) {
    a.x += __shfl_xor(a.x, m, 64);
    a.y += __shfl_xor(a.y, m, 64);
    a.z += __shfl_xor(a.z, m, 64);
    a.w += __shfl_xor(a.w, m, 64);
    den += __shfl_xor(den, m, 64);
  }

  if (g == 0) {
    const float4 bv = *(const float4*)(b + c4);
    const float inv = 1.f / den;
    float4 r;
    r.x = a.x * inv + bv.x;
    r.y = a.y * inv + bv.y;
    r.z = a.z * inv + bv.z;
    r.w = a.w * inv + bv.w;
    *(float4*)(out + (size_t)n * 32 + c4) = r;
  }
}

// ===========================================================================
extern "C" void kernel_launch(void* const* d_in, const int* in_sizes, int n_in,
                              void* d_out, int out_size, void* d_ws, size_t ws_size,
                              hipStream_t stream)
{
  const float* x   = (const float*)d_in[0];
  const int*   ei  = (const int*)  d_in[1];
  const float* W1  = (const float*)d_in[2];
  const float* as1 = (const float*)d_in[3];
  const float* ad1 = (const float*)d_in[4];
  const float* b1  = (const float*)d_in[5];
  const float* W2  = (const float*)d_in[6];
  const float* as2 = (const float*)d_in[7];
  const float* ad2 = (const float*)d_in[8];
  const float* b2  = (const float*)d_in[9];

  const int N = in_sizes[0] / 128;
  const int E = in_sizes[1] / 2;

  // workspace layout
  char* p = (char*)d_ws;
  int* counts  = (int*)p;                p += (size_t)N * 4;
  int* cursor  = (int*)p;                p += (size_t)N * 4;
  int* offs    = (int*)p;                p += (size_t)(N + 1) * 4;
  int* partial = (int*)p;                p += (size_t)SCAN_BLOCKS * 4;
  int* ssrc    = (int*)p;                p += (size_t)E * 4;
  int* sdst    = (int*)p;                p += (size_t)E * 4;
  float2* ew1  = (float2*)p;             p += (size_t)E * 8;
  float* ew2   = (float*)p;              p += (size_t)E * 4;
  float* h1    = (float*)p;              p += (size_t)N * 128 * 4;
  float* out1  = (float*)p;              p += (size_t)N * 128 * 4;
  float* asrc1 = (float*)p;              p += (size_t)N * 2 * 4;
  float* adst1 = (float*)p;              p += (size_t)N * 2 * 4;
  float* h2    = (float*)p;              p += (size_t)N * 32 * 4;
  float* asrc2 = (float*)p;              p += (size_t)N * 4;
  float* adst2 = (float*)p;              p += (size_t)N * 4;
  float* out   = (float*)d_out;          // N*32

  // ---- Phase A: dst-sorted CSR ----
  hipMemsetAsync(counts, 0, (size_t)N * 4, stream);
  hist_kernel<<<(E + 255) / 256, 256, 0, stream>>>(ei, counts, E);
  scan_a<<<SCAN_BLOCKS, 256, 0, stream>>>(counts, partial, N);
  scan_c<<<SCAN_BLOCKS, 256, 0, stream>>>(counts, partial, offs, cursor, N);
  scatter_kernel<<<(E + 255) / 256, 256, 0, stream>>>(ei, cursor, ssrc, sdst, E);

  // ---- layer 1 ----
  gemm1_kernel<<<(N + BM1 - 1) / BM1, 256, 0, stream>>>(x, W1, as1, ad1,
                                                        h1, asrc1, adst1, N);
  edgew1_kernel<<<(E + 255) / 256, 256, 0, stream>>>(ssrc, sdst, asrc1, adst1, ew1, E);
  agg1_kernel<<<(N * 64 + 255) / 256, 256, 0, stream>>>(offs, ssrc, ew1, h1,
                                                        asrc1, adst1, b1, out1, N);

  // ---- layer 2 ----
  gemm2_kernel<<<(N + BM2 - 1) / BM2, 256, 0, stream>>>(out1, W2, as2, ad2,
                                                        h2, asrc2, adst2, N);
  edgew2_kernel<<<(E + 255) / 256, 256, 0, stream>>>(ssrc, sdst, asrc2, adst2, ew2, E);
  agg2_kernel<<<(N * 64 + 255) / 256, 256, 0, stream>>>(offs, ssrc, ew2, h2,
                                                        asrc2, adst2, b2, out, N);
}

// Round 7
// 313.672 us; speedup vs baseline: 1.1718x; 1.1718x over previous
//
#include <hip/hip_runtime.h>

#define NEG 0.2f

constexpr int SCAN_BLOCKS = 64;

// ===========================================================================
// Phase A: build dst-sorted CSR (shared by both GAT layers)
// ===========================================================================
__global__ void hist_kernel(const int* __restrict__ ei, int* __restrict__ counts, int E)
{
  const int i = blockIdx.x * 256 + threadIdx.x;
  if (i < E) atomicAdd(&counts[ei[E + i]], 1);
}

__global__ __launch_bounds__(256) void scan_a(const int* __restrict__ counts,
                                              int* __restrict__ partial, int N)
{
  const int b = blockIdx.x, t = threadIdx.x;
  const int per_block = (N + SCAN_BLOCKS - 1) / SCAN_BLOCKS;
  const int beg = b * per_block;
  const int end = min(beg + per_block, N);
  int s = 0;
  for (int i = beg + t; i < end; i += 256) s += counts[i];
#pragma unroll
  for (int m = 32; m >= 1; m >>= 1) s += __shfl_xor(s, m, 64);
  __shared__ int ws[4];
  if ((t & 63) == 0) ws[t >> 6] = s;
  __syncthreads();
  if (t == 0) partial[b] = ws[0] + ws[1] + ws[2] + ws[3];
}

__global__ __launch_bounds__(256) void scan_c(const int* __restrict__ counts,
                                              const int* __restrict__ partial,
                                              int* __restrict__ offs,
                                              int* __restrict__ cursor, int N)
{
  const int b = blockIdx.x, t = threadIdx.x;
  const int per_block = (N + SCAN_BLOCKS - 1) / SCAN_BLOCKS;
  const int per_thread = (per_block + 255) / 256;
  const int beg = b * per_block;
  const int end = min(beg + per_block, N);

  int base = 0;
  for (int i = 0; i < SCAN_BLOCKS; ++i)
    if (i < b) base += partial[i];

  const int tbeg = beg + t * per_thread;
  const int tend = min(tbeg + per_thread, end);
  int tsum = 0;
  for (int i = tbeg; i < tend; ++i) tsum += counts[i];

  __shared__ int sums[256];
  sums[t] = tsum;
  __syncthreads();
  for (int off = 1; off < 256; off <<= 1) {
    int v = (t >= off) ? sums[t - off] : 0;
    __syncthreads();
    if (t >= off) sums[t] += v;
    __syncthreads();
  }
  int run = base + (t ? sums[t - 1] : 0);
  for (int i = tbeg; i < tend; ++i) {
    offs[i] = run;
    cursor[i] = run;
    run += counts[i];
  }
  if (b == SCAN_BLOCKS - 1 && t == 255) offs[N] = base + sums[255];
}

__global__ void scatter_kernel(const int* __restrict__ ei, int* __restrict__ cursor,
                               int* __restrict__ ssrc, int* __restrict__ sdst, int E)
{
  const int i = blockIdx.x * 256 + threadIdx.x;
  if (i < E) {
    const int d = ei[E + i];
    const int pos = atomicAdd(&cursor[d], 1);
    ssrc[pos] = ei[i];
    sdst[pos] = d;
  }
}

// ===========================================================================
// Edge-parallel softmax-weight precompute
// ===========================================================================
__global__ void edgew1_kernel(const int* __restrict__ ssrc, const int* __restrict__ sdst,
                              const float* __restrict__ asrc, const float* __restrict__ adst,
                              float2* __restrict__ ew, int E)
{
  const int i = blockIdx.x * 256 + threadIdx.x;
  if (i >= E) return;
  const int s = ssrc[i], d = sdst[i];
  const float2 av = *(const float2*)(asrc + 2 * s);
  const float2 dv = *(const float2*)(adst + 2 * d);
  float e0 = av.x + dv.x, e1 = av.y + dv.y;
  e0 = e0 > 0.f ? e0 : NEG * e0;
  e1 = e1 > 0.f ? e1 : NEG * e1;
  ew[i] = make_float2(__expf(e0), __expf(e1));
}

__global__ void edgew2_kernel(const int* __restrict__ ssrc, const int* __restrict__ sdst,
                              const float* __restrict__ asrc, const float* __restrict__ adst,
                              float* __restrict__ ew, int E)
{
  const int i = blockIdx.x * 256 + threadIdx.x;
  if (i >= E) return;
  float e = asrc[ssrc[i]] + adst[sdst[i]];
  e = e > 0.f ? e : NEG * e;
  ew[i] = __expf(e);
}

// ===========================================================================
// GEMM1: h1 = x @ W1  (N x 128)@(128 x 128). LDS-tiled: BM=32 nodes/block,
// 256 thr, thread = 4 nodes x 4 cols. Unroll pinned, VGPR capped.
// ===========================================================================
constexpr int BM1 = 32;

__global__ __launch_bounds__(256, 4) void gemm1_kernel(
    const float* __restrict__ x, const float* __restrict__ W,
    const float* __restrict__ a_src, const float* __restrict__ a_dst,
    float* __restrict__ h, float* __restrict__ asrc, float* __restrict__ adst,
    int N)
{
  __shared__ float xs[BM1][132];   // +4 pad: conflict-free b128 reads
  const int t = threadIdx.x;
  const int n0 = blockIdx.x * BM1;

#pragma unroll
  for (int i = 0; i < 4; ++i) {
    const int idx = t + i * 256;       // float4 slot 0..1023
    const int row = idx >> 5;
    const int cq  = idx & 31;
    int rn = n0 + row; if (rn >= N) rn = N - 1;
    *(float4*)&xs[row][cq * 4] = *(const float4*)(x + (size_t)rn * 128 + cq * 4);
  }
  __syncthreads();

  const int c4 = (t & 31) << 2;        // cols c4..c4+3
  const int tn = (t >> 5) << 2;        // first of 4 local nodes

  float4 acc[4];
#pragma unroll
  for (int j = 0; j < 4; ++j) acc[j] = make_float4(0.f, 0.f, 0.f, 0.f);

#pragma unroll 4
  for (int k0 = 0; k0 < 128; k0 += 4) {
    const float4 w0 = *(const float4*)(W + (k0 + 0) * 128 + c4);
    const float4 w1 = *(const float4*)(W + (k0 + 1) * 128 + c4);
    const float4 w2 = *(const float4*)(W + (k0 + 2) * 128 + c4);
    const float4 w3 = *(const float4*)(W + (k0 + 3) * 128 + c4);
#pragma unroll
    for (int j = 0; j < 4; ++j) {
      const float4 xv = *(const float4*)&xs[tn + j][k0];
      acc[j].x += xv.x * w0.x + xv.y * w1.x + xv.z * w2.x + xv.w * w3.x;
      acc[j].y += xv.x * w0.y + xv.y * w1.y + xv.z * w2.y + xv.w * w3.y;
      acc[j].z += xv.x * w0.z + xv.y * w1.z + xv.z * w2.z + xv.w * w3.z;
      acc[j].w += xv.x * w0.w + xv.y * w1.w + xv.z * w2.w + xv.w * w3.w;
    }
  }

  const float4 avs = *(const float4*)(a_src + c4);
  const float4 avd = *(const float4*)(a_dst + c4);
  const int head = (t >> 4) & 1;

#pragma unroll
  for (int j = 0; j < 4; ++j) {
    const int nn = n0 + tn + j;
    if (nn >= N) break;
    *(float4*)(h + (size_t)nn * 128 + c4) = acc[j];
    float vs = acc[j].x * avs.x + acc[j].y * avs.y + acc[j].z * avs.z + acc[j].w * avs.w;
    float vd = acc[j].x * avd.x + acc[j].y * avd.y + acc[j].z * avd.z + acc[j].w * avd.w;
#pragma unroll
    for (int m = 1; m <= 8; m <<= 1) {
      vs += __shfl_xor(vs, m, 64);
      vd += __shfl_xor(vd, m, 64);
    }
    if ((t & 15) == 0) {
      asrc[nn * 2 + head] = vs;
      adst[nn * 2 + head] = vd;
    }
  }
}

// ===========================================================================
// GEMM2: h2 = out1 @ W2  (N x 128)@(128 x 32). BM=32 nodes/block, 256 thr,
// thread = 1 node x 4 cols (acc = one float4). x-tile AND W2 staged in LDS.
// k is wave-uniform -> W2 LDS reads are broadcast, bank-clean without pad.
// ===========================================================================
constexpr int BM2 = 32;

__global__ __launch_bounds__(256, 4) void gemm2_kernel(
    const float* __restrict__ x, const float* __restrict__ W,
    const float* __restrict__ a_src, const float* __restrict__ a_dst,
    float* __restrict__ h, float* __restrict__ asrc, float* __restrict__ adst,
    int N)
{
  __shared__ float xs[BM2][132];
  __shared__ float ws[128][32];
  const int t = threadIdx.x;
  const int n0 = blockIdx.x * BM2;

  // stage x tile (32x128)
#pragma unroll
  for (int i = 0; i < 4; ++i) {
    const int idx = t + i * 256;
    const int row = idx >> 5;
    const int cq  = idx & 31;
    int rn = n0 + row; if (rn >= N) rn = N - 1;
    *(float4*)&xs[row][cq * 4] = *(const float4*)(x + (size_t)rn * 128 + cq * 4);
  }
  // stage W2 (128x32 = 1024 float4)
#pragma unroll
  for (int i = 0; i < 4; ++i) {
    const int idx = t + i * 256;       // float4 slot 0..1023
    const int row = idx >> 3;          // k row 0..127
    const int cq  = idx & 7;           // col quad 0..7
    *(float4*)&ws[row][cq * 4] = *(const float4*)(W + row * 32 + cq * 4);
  }
  __syncthreads();

  const int c4 = (t & 7) << 2;         // cols c4..c4+3 (of 32)
  const int tn = t >> 3;               // local node 0..31

  float4 acc = make_float4(0.f, 0.f, 0.f, 0.f);

#pragma unroll 4
  for (int k0 = 0; k0 < 128; k0 += 4) {
    const float4 w0 = *(const float4*)&ws[k0 + 0][c4];
    const float4 w1 = *(const float4*)&ws[k0 + 1][c4];
    const float4 w2 = *(const float4*)&ws[k0 + 2][c4];
    const float4 w3 = *(const float4*)&ws[k0 + 3][c4];
    const float4 xv = *(const float4*)&xs[tn][k0];
    acc.x += xv.x * w0.x + xv.y * w1.x + xv.z * w2.x + xv.w * w3.x;
    acc.y += xv.x * w0.y + xv.y * w1.y + xv.z * w2.y + xv.w * w3.y;
    acc.z += xv.x * w0.z + xv.y * w1.z + xv.z * w2.z + xv.w * w3.z;
    acc.w += xv.x * w0.w + xv.y * w1.w + xv.z * w2.w + xv.w * w3.w;
  }

  const int nn = n0 + tn;
  if (nn < N) {
    *(float4*)(h + (size_t)nn * 32 + c4) = acc;

    const float4 avs = *(const float4*)(a_src + c4);
    const float4 avd = *(const float4*)(a_dst + c4);
    float vs = acc.x * avs.x + acc.y * avs.y + acc.z * avs.z + acc.w * avs.w;
    float vd = acc.x * avd.x + acc.y * avd.y + acc.z * avd.z + acc.w * avd.w;
#pragma unroll
    for (int m = 1; m <= 4; m <<= 1) {
      vs += __shfl_xor(vs, m, 64);
      vd += __shfl_xor(vd, m, 64);
    }
    if ((t & 7) == 0) {
      asrc[nn] = vs;
      adst[nn] = vd;
    }
  }
}

// ===========================================================================
// Layer-1 segment aggregation (unchanged)
// ===========================================================================
__global__ __launch_bounds__(256) void agg1_kernel(
    const int* __restrict__ offs, const int* __restrict__ ssrc,
    const float2* __restrict__ ew,
    const float* __restrict__ h, const float* __restrict__ asrc,
    const float* __restrict__ adst, const float* __restrict__ b,
    float* __restrict__ out, int N)
{
  const int n = (blockIdx.x * 256 + threadIdx.x) >> 6;
  const int lane = threadIdx.x & 63;
  const int c = lane & 31;
  const int half = lane >> 5;
  const int head = c >> 4;
  if (n >= N) return;

  float4 a = make_float4(0.f, 0.f, 0.f, 0.f);
  float den = 0.f;

  const int beg = offs[n];
  const int end = offs[n + 1];

  for (int i0 = beg + half; i0 < end; i0 += 8) {
    const int i1 = i0 + 2, i2 = i0 + 4, i3 = i0 + 6;
    const bool v1 = i1 < end, v2 = i2 < end, v3 = i3 < end;

    const int s0 = ssrc[i0];
    const int s1 = v1 ? ssrc[i1] : s0;
    const int s2 = v2 ? ssrc[i2] : s0;
    const int s3 = v3 ? ssrc[i3] : s0;

    const float2 ww0 = ew[i0];
    const float2 ww1 = v1 ? ew[i1] : make_float2(0.f, 0.f);
    const float2 ww2 = v2 ? ew[i2] : make_float2(0.f, 0.f);
    const float2 ww3 = v3 ? ew[i3] : make_float2(0.f, 0.f);

    const float4 h0 = *(const float4*)(h + (size_t)s0 * 128 + c * 4);
    const float4 h1 = *(const float4*)(h + (size_t)s1 * 128 + c * 4);
    const float4 h2 = *(const float4*)(h + (size_t)s2 * 128 + c * 4);
    const float4 h3 = *(const float4*)(h + (size_t)s3 * 128 + c * 4);

    const float w0 = head ? ww0.y : ww0.x;
    const float w1 = head ? ww1.y : ww1.x;
    const float w2 = head ? ww2.y : ww2.x;
    const float w3 = head ? ww3.y : ww3.x;

    den += (w0 + w1) + (w2 + w3);
    a.x += w0 * h0.x + w1 * h1.x + w2 * h2.x + w3 * h3.x;
    a.y += w0 * h0.y + w1 * h1.y + w2 * h2.y + w3 * h3.y;
    a.z += w0 * h0.z + w1 * h1.z + w2 * h2.z + w3 * h3.z;
    a.w += w0 * h0.w + w1 * h1.w + w2 * h2.w + w3 * h3.w;
  }

  if (half == 0) {  // self-loop
    const float2 asv = *(const float2*)(asrc + 2 * n);
    const float2 adv = *(const float2*)(adst + 2 * n);
    float e = head ? (asv.y + adv.y) : (asv.x + adv.x);
    e = e > 0.f ? e : NEG * e;
    const float w = __expf(e);
    den += w;
    const float4 hv = *(const float4*)(h + (size_t)n * 128 + c * 4);
    a.x += w * hv.x; a.y += w * hv.y; a.z += w * hv.z; a.w += w * hv.w;
  }

  a.x += __shfl_xor(a.x, 32, 64);
  a.y += __shfl_xor(a.y, 32, 64);
  a.z += __shfl_xor(a.z, 32, 64);
  a.w += __shfl_xor(a.w, 32, 64);
  den += __shfl_xor(den, 32, 64);

  if (half == 0) {
    const float4 bv = *(const float4*)(b + c * 4);
    const float inv = 1.f / den;
    float4 r;
    r.x = a.x * inv + bv.x;
    r.y = a.y * inv + bv.y;
    r.z = a.z * inv + bv.z;
    r.w = a.w * inv + bv.w;
    r.x = r.x > 0.f ? r.x : 0.f;
    r.y = r.y > 0.f ? r.y : 0.f;
    r.z = r.z > 0.f ? r.z : 0.f;
    r.w = r.w > 0.f ? r.w : 0.f;
    *(float4*)(out + (size_t)n * 128 + c * 4) = r;
  }
}

// ===========================================================================
// Layer-2 segment aggregation (unchanged)
// ===========================================================================
__global__ __launch_bounds__(256) void agg2_kernel(
    const int* __restrict__ offs, const int* __restrict__ ssrc,
    const float* __restrict__ ew,
    const float* __restrict__ h, const float* __restrict__ asrc,
    const float* __restrict__ adst, const float* __restrict__ b,
    float* __restrict__ out, int N)
{
  const int n = (blockIdx.x * 256 + threadIdx.x) >> 6;
  const int lane = threadIdx.x & 63;
  const int g = lane >> 3;
  const int c4 = (lane & 7) << 2;
  if (n >= N) return;

  float4 a = make_float4(0.f, 0.f, 0.f, 0.f);
  float den = 0.f;

  const int beg = offs[n];
  const int end = offs[n + 1];

  for (int i0 = beg + g; i0 < end; i0 += 16) {
    const int i1 = i0 + 8;
    const bool v1 = i1 < end;

    const int s0 = ssrc[i0];
    const int s1 = v1 ? ssrc[i1] : s0;
    const float w0 = ew[i0];
    const float w1 = v1 ? ew[i1] : 0.f;

    const float4 h0 = *(const float4*)(h + (size_t)s0 * 32 + c4);
    const float4 h1 = *(const float4*)(h + (size_t)s1 * 32 + c4);

    den += w0 + w1;
    a.x += w0 * h0.x + w1 * h1.x;
    a.y += w0 * h0.y + w1 * h1.y;
    a.z += w0 * h0.z + w1 * h1.z;
    a.w += w0 * h0.w + w1 * h1.w;
  }

  if (g == 0) {  // self-loop
    float e = asrc[n] + adst[n];
    e = e > 0.f ? e : NEG * e;
    const float w = __expf(e);
    den += w;
    const float4 hv = *(const float4*)(h + (size_t)n * 32 + c4);
    a.x += w * hv.x; a.y += w * hv.y; a.z += w * hv.z; a.w += w * hv.w;
  }

#pragma unroll
  for (int m = 8; m <= 32; m <<= 1) {
    a.x += __shfl_xor(a.x, m, 64);
    a.y += __shfl_xor(a.y, m, 64);
    a.z += __shfl_xor(a.z, m, 64);
    a.w += __shfl_xor(a.w, m, 64);
    den += __shfl_xor(den, m, 64);
  }

  if (g == 0) {
    const float4 bv = *(const float4*)(b + c4);
    const float inv = 1.f / den;
    float4 r;
    r.x = a.x * inv + bv.x;
    r.y = a.y * inv + bv.y;
    r.z = a.z * inv + bv.z;
    r.w = a.w * inv + bv.w;
    *(float4*)(out + (size_t)n * 32 + c4) = r;
  }
}

// ===========================================================================
extern "C" void kernel_launch(void* const* d_in, const int* in_sizes, int n_in,
                              void* d_out, int out_size, void* d_ws, size_t ws_size,
                              hipStream_t stream)
{
  const float* x   = (const float*)d_in[0];
  const int*   ei  = (const int*)  d_in[1];
  const float* W1  = (const float*)d_in[2];
  const float* as1 = (const float*)d_in[3];
  const float* ad1 = (const float*)d_in[4];
  const float* b1  = (const float*)d_in[5];
  const float* W2  = (const float*)d_in[6];
  const float* as2 = (const float*)d_in[7];
  const float* ad2 = (const float*)d_in[8];
  const float* b2  = (const float*)d_in[9];

  const int N = in_sizes[0] / 128;
  const int E = in_sizes[1] / 2;

  // workspace layout
  char* p = (char*)d_ws;
  int* counts  = (int*)p;                p += (size_t)N * 4;
  int* cursor  = (int*)p;                p += (size_t)N * 4;
  int* offs    = (int*)p;                p += (size_t)(N + 1) * 4;
  int* partial = (int*)p;                p += (size_t)SCAN_BLOCKS * 4;
  int* ssrc    = (int*)p;                p += (size_t)E * 4;
  int* sdst    = (int*)p;                p += (size_t)E * 4;
  float2* ew1  = (float2*)p;             p += (size_t)E * 8;
  float* ew2   = (float*)p;              p += (size_t)E * 4;
  float* h1    = (float*)p;              p += (size_t)N * 128 * 4;
  float* out1  = (float*)p;              p += (size_t)N * 128 * 4;
  float* asrc1 = (float*)p;              p += (size_t)N * 2 * 4;
  float* adst1 = (float*)p;              p += (size_t)N * 2 * 4;
  float* h2    = (float*)p;              p += (size_t)N * 32 * 4;
  float* asrc2 = (float*)p;              p += (size_t)N * 4;
  float* adst2 = (float*)p;              p += (size_t)N * 4;
  float* out   = (float*)d_out;          // N*32

  // ---- Phase A: dst-sorted CSR ----
  hipMemsetAsync(counts, 0, (size_t)N * 4, stream);
  hist_kernel<<<(E + 255) / 256, 256, 0, stream>>>(ei, counts, E);
  scan_a<<<SCAN_BLOCKS, 256, 0, stream>>>(counts, partial, N);
  scan_c<<<SCAN_BLOCKS, 256, 0, stream>>>(counts, partial, offs, cursor, N);
  scatter_kernel<<<(E + 255) / 256, 256, 0, stream>>>(ei, cursor, ssrc, sdst, E);

  // ---- layer 1 ----
  gemm1_kernel<<<(N + BM1 - 1) / BM1, 256, 0, stream>>>(x, W1, as1, ad1,
                                                        h1, asrc1, adst1, N);
  edgew1_kernel<<<(E + 255) / 256, 256, 0, stream>>>(ssrc, sdst, asrc1, adst1, ew1, E);
  agg1_kernel<<<(N * 64 + 255) / 256, 256, 0, stream>>>(offs, ssrc, ew1, h1,
                                                        asrc1, adst1, b1, out1, N);

  // ---- layer 2 ----
  gemm2_kernel<<<(N + BM2 - 1) / BM2, 256, 0, stream>>>(out1, W2, as2, ad2,
                                                        h2, asrc2, adst2, N);
  edgew2_kernel<<<(E + 255) / 256, 256, 0, stream>>>(ssrc, sdst, asrc2, adst2, ew2, E);
  agg2_kernel<<<(N * 64 + 255) / 256, 256, 0, stream>>>(offs, ssrc, ew2, h2,
                                                        asrc2, adst2, b2, out, N);
}

// Round 8
// 309.442 us; speedup vs baseline: 1.1878x; 1.0137x over previous
//
#include <hip/hip_runtime.h>

#define NEG 0.2f

constexpr int SCAN_BLOCKS = 64;

// bf16 helpers (RNE convert; bf16->f32 is exact via bit shift)
__device__ __forceinline__ ushort f2bf(float f) {
  uint u = __float_as_uint(f);
  return (ushort)((u + 0x7fffu + ((u >> 16) & 1u)) >> 16);
}
__device__ __forceinline__ float bf2f(ushort v) {
  return __uint_as_float((uint)v << 16);
}

// ===========================================================================
// Phase A: build dst-sorted CSR (shared by both GAT layers)
// ===========================================================================
__global__ void hist_kernel(const int* __restrict__ ei, int* __restrict__ counts, int E)
{
  const int i = blockIdx.x * 256 + threadIdx.x;
  if (i < E) atomicAdd(&counts[ei[E + i]], 1);
}

__global__ __launch_bounds__(256) void scan_a(const int* __restrict__ counts,
                                              int* __restrict__ partial, int N)
{
  const int b = blockIdx.x, t = threadIdx.x;
  const int per_block = (N + SCAN_BLOCKS - 1) / SCAN_BLOCKS;
  const int beg = b * per_block;
  const int end = min(beg + per_block, N);
  int s = 0;
  for (int i = beg + t; i < end; i += 256) s += counts[i];
#pragma unroll
  for (int m = 32; m >= 1; m >>= 1) s += __shfl_xor(s, m, 64);
  __shared__ int ws[4];
  if ((t & 63) == 0) ws[t >> 6] = s;
  __syncthreads();
  if (t == 0) partial[b] = ws[0] + ws[1] + ws[2] + ws[3];
}

__global__ __launch_bounds__(256) void scan_c(const int* __restrict__ counts,
                                              const int* __restrict__ partial,
                                              int* __restrict__ offs,
                                              int* __restrict__ cursor, int N)
{
  const int b = blockIdx.x, t = threadIdx.x;
  const int per_block = (N + SCAN_BLOCKS - 1) / SCAN_BLOCKS;
  const int per_thread = (per_block + 255) / 256;
  const int beg = b * per_block;
  const int end = min(beg + per_block, N);

  int base = 0;
  for (int i = 0; i < SCAN_BLOCKS; ++i)
    if (i < b) base += partial[i];

  const int tbeg = beg + t * per_thread;
  const int tend = min(tbeg + per_thread, end);
  int tsum = 0;
  for (int i = tbeg; i < tend; ++i) tsum += counts[i];

  __shared__ int sums[256];
  sums[t] = tsum;
  __syncthreads();
  for (int off = 1; off < 256; off <<= 1) {
    int v = (t >= off) ? sums[t - off] : 0;
    __syncthreads();
    if (t >= off) sums[t] += v;
    __syncthreads();
  }
  int run = base + (t ? sums[t - 1] : 0);
  for (int i = tbeg; i < tend; ++i) {
    offs[i] = run;
    cursor[i] = run;
    run += counts[i];
  }
  if (b == SCAN_BLOCKS - 1 && t == 255) offs[N] = base + sums[255];
}

__global__ void scatter_kernel(const int* __restrict__ ei, int* __restrict__ cursor,
                               int* __restrict__ ssrc, int* __restrict__ sdst, int E)
{
  const int i = blockIdx.x * 256 + threadIdx.x;
  if (i < E) {
    const int d = ei[E + i];
    const int pos = atomicAdd(&cursor[d], 1);
    ssrc[pos] = ei[i];
    sdst[pos] = d;
  }
}

// ===========================================================================
// Edge-parallel softmax-weight precompute
// ===========================================================================
__global__ void edgew1_kernel(const int* __restrict__ ssrc, const int* __restrict__ sdst,
                              const float* __restrict__ asrc, const float* __restrict__ adst,
                              float2* __restrict__ ew, int E)
{
  const int i = blockIdx.x * 256 + threadIdx.x;
  if (i >= E) return;
  const int s = ssrc[i], d = sdst[i];
  const float2 av = *(const float2*)(asrc + 2 * s);
  const float2 dv = *(const float2*)(adst + 2 * d);
  float e0 = av.x + dv.x, e1 = av.y + dv.y;
  e0 = e0 > 0.f ? e0 : NEG * e0;
  e1 = e1 > 0.f ? e1 : NEG * e1;
  ew[i] = make_float2(__expf(e0), __expf(e1));
}

__global__ void edgew2_kernel(const int* __restrict__ ssrc, const int* __restrict__ sdst,
                              const float* __restrict__ asrc, const float* __restrict__ adst,
                              float* __restrict__ ew, int E)
{
  const int i = blockIdx.x * 256 + threadIdx.x;
  if (i >= E) return;
  float e = asrc[ssrc[i]] + adst[sdst[i]];
  e = e > 0.f ? e : NEG * e;
  ew[i] = __expf(e);
}

// ===========================================================================
// GEMM1: h1 = x @ W1  (N x 128)@(128 x 128). LDS-tiled x AND W (32-row
// chunks). Inner loop pure LDS + FMA. h1 stored bf16; alphas fp32.
// ===========================================================================
constexpr int BM1 = 32;

__global__ __launch_bounds__(256, 4) void gemm1_kernel(
    const float* __restrict__ x, const float* __restrict__ W,
    const float* __restrict__ a_src, const float* __restrict__ a_dst,
    ushort* __restrict__ h, float* __restrict__ asrc, float* __restrict__ adst,
    int N)
{
  __shared__ float xs[BM1][132];   // +4 pad
  __shared__ float wsm[32][128];   // one 32-k-row chunk of W
  const int t = threadIdx.x;
  const int n0 = blockIdx.x * BM1;

  // stage x tile (32x128, coalesced float4)
#pragma unroll
  for (int i = 0; i < 4; ++i) {
    const int idx = t + i * 256;
    const int row = idx >> 5;
    const int cq  = idx & 31;
    int rn = n0 + row; if (rn >= N) rn = N - 1;
    *(float4*)&xs[row][cq * 4] = *(const float4*)(x + (size_t)rn * 128 + cq * 4);
  }

  const int c4 = (t & 31) << 2;        // cols c4..c4+3
  const int tn = (t >> 5) << 2;        // first of 4 local nodes

  float4 acc[4];
#pragma unroll
  for (int j = 0; j < 4; ++j) acc[j] = make_float4(0.f, 0.f, 0.f, 0.f);

  for (int kc = 0; kc < 4; ++kc) {
    __syncthreads();   // xs ready (kc=0) / previous chunk consumed
    // stage W rows kc*32 .. kc*32+31 (32x128 = 1024 float4)
#pragma unroll
    for (int i = 0; i < 4; ++i) {
      const int idx = t + i * 256;
      const int row = idx >> 5;
      const int cq  = idx & 31;
      *(float4*)&wsm[row][cq * 4] =
          *(const float4*)(W + (size_t)(kc * 32 + row) * 128 + cq * 4);
    }
    __syncthreads();

#pragma unroll
    for (int kk = 0; kk < 32; kk += 4) {
      const float4 w0 = *(const float4*)&wsm[kk + 0][c4];
      const float4 w1 = *(const float4*)&wsm[kk + 1][c4];
      const float4 w2 = *(const float4*)&wsm[kk + 2][c4];
      const float4 w3 = *(const float4*)&wsm[kk + 3][c4];
      const int k0 = kc * 32 + kk;
#pragma unroll
      for (int j = 0; j < 4; ++j) {
        const float4 xv = *(const float4*)&xs[tn + j][k0];
        acc[j].x += xv.x * w0.x + xv.y * w1.x + xv.z * w2.x + xv.w * w3.x;
        acc[j].y += xv.x * w0.y + xv.y * w1.y + xv.z * w2.y + xv.w * w3.y;
        acc[j].z += xv.x * w0.z + xv.y * w1.z + xv.z * w2.z + xv.w * w3.z;
        acc[j].w += xv.x * w0.w + xv.y * w1.w + xv.z * w2.w + xv.w * w3.w;
      }
    }
  }

  const float4 avs = *(const float4*)(a_src + c4);
  const float4 avd = *(const float4*)(a_dst + c4);
  const int head = (t >> 4) & 1;

#pragma unroll
  for (int j = 0; j < 4; ++j) {
    const int nn = n0 + tn + j;
    if (nn >= N) break;
    ushort4 hv;
    hv.x = f2bf(acc[j].x); hv.y = f2bf(acc[j].y);
    hv.z = f2bf(acc[j].z); hv.w = f2bf(acc[j].w);
    *(ushort4*)(h + (size_t)nn * 128 + c4) = hv;
    float vs = acc[j].x * avs.x + acc[j].y * avs.y + acc[j].z * avs.z + acc[j].w * avs.w;
    float vd = acc[j].x * avd.x + acc[j].y * avd.y + acc[j].z * avd.z + acc[j].w * avd.w;
#pragma unroll
    for (int m = 1; m <= 8; m <<= 1) {
      vs += __shfl_xor(vs, m, 64);
      vd += __shfl_xor(vd, m, 64);
    }
    if ((t & 15) == 0) {
      asrc[nn * 2 + head] = vs;
      adst[nn * 2 + head] = vd;
    }
  }
}

// ===========================================================================
// GEMM2: h2 = out1 @ W2  (N x 128)@(128 x 32). x-tile + W2 in LDS.
// ===========================================================================
constexpr int BM2 = 32;

__global__ __launch_bounds__(256, 4) void gemm2_kernel(
    const float* __restrict__ x, const float* __restrict__ W,
    const float* __restrict__ a_src, const float* __restrict__ a_dst,
    float* __restrict__ h, float* __restrict__ asrc, float* __restrict__ adst,
    int N)
{
  __shared__ float xs[BM2][132];
  __shared__ float wsm[128][32];
  const int t = threadIdx.x;
  const int n0 = blockIdx.x * BM2;

#pragma unroll
  for (int i = 0; i < 4; ++i) {
    const int idx = t + i * 256;
    const int row = idx >> 5;
    const int cq  = idx & 31;
    int rn = n0 + row; if (rn >= N) rn = N - 1;
    *(float4*)&xs[row][cq * 4] = *(const float4*)(x + (size_t)rn * 128 + cq * 4);
  }
#pragma unroll
  for (int i = 0; i < 4; ++i) {
    const int idx = t + i * 256;       // float4 slot 0..1023
    const int row = idx >> 3;          // k row 0..127
    const int cq  = idx & 7;           // col quad 0..7
    *(float4*)&wsm[row][cq * 4] = *(const float4*)(W + row * 32 + cq * 4);
  }
  __syncthreads();

  const int c4 = (t & 7) << 2;
  const int tn = t >> 3;

  float4 acc = make_float4(0.f, 0.f, 0.f, 0.f);

#pragma unroll 4
  for (int k0 = 0; k0 < 128; k0 += 4) {
    const float4 w0 = *(const float4*)&wsm[k0 + 0][c4];
    const float4 w1 = *(const float4*)&wsm[k0 + 1][c4];
    const float4 w2 = *(const float4*)&wsm[k0 + 2][c4];
    const float4 w3 = *(const float4*)&wsm[k0 + 3][c4];
    const float4 xv = *(const float4*)&xs[tn][k0];
    acc.x += xv.x * w0.x + xv.y * w1.x + xv.z * w2.x + xv.w * w3.x;
    acc.y += xv.x * w0.y + xv.y * w1.y + xv.z * w2.y + xv.w * w3.y;
    acc.z += xv.x * w0.z + xv.y * w1.z + xv.z * w2.z + xv.w * w3.z;
    acc.w += xv.x * w0.w + xv.y * w1.w + xv.z * w2.w + xv.w * w3.w;
  }

  const int nn = n0 + tn;
  if (nn < N) {
    *(float4*)(h + (size_t)nn * 32 + c4) = acc;

    const float4 avs = *(const float4*)(a_src + c4);
    const float4 avd = *(const float4*)(a_dst + c4);
    float vs = acc.x * avs.x + acc.y * avs.y + acc.z * avs.z + acc.w * avs.w;
    float vd = acc.x * avd.x + acc.y * avd.y + acc.z * avd.z + acc.w * avd.w;
#pragma unroll
    for (int m = 1; m <= 4; m <<= 1) {
      vs += __shfl_xor(vs, m, 64);
      vd += __shfl_xor(vd, m, 64);
    }
    if ((t & 7) == 0) {
      asrc[nn] = vs;
      adst[nn] = vd;
    }
  }
}

// ===========================================================================
// Layer-1 segment aggregation: h1 is bf16 (half the gather bytes).
// ===========================================================================
__global__ __launch_bounds__(256) void agg1_kernel(
    const int* __restrict__ offs, const int* __restrict__ ssrc,
    const float2* __restrict__ ew,
    const ushort* __restrict__ h, const float* __restrict__ asrc,
    const float* __restrict__ adst, const float* __restrict__ b,
    float* __restrict__ out, int N)
{
  const int n = (blockIdx.x * 256 + threadIdx.x) >> 6;
  const int lane = threadIdx.x & 63;
  const int c = lane & 31;
  const int half = lane >> 5;
  const int head = c >> 4;
  if (n >= N) return;

  float4 a = make_float4(0.f, 0.f, 0.f, 0.f);
  float den = 0.f;

  const int beg = offs[n];
  const int end = offs[n + 1];

  for (int i0 = beg + half; i0 < end; i0 += 8) {
    const int i1 = i0 + 2, i2 = i0 + 4, i3 = i0 + 6;
    const bool v1 = i1 < end, v2 = i2 < end, v3 = i3 < end;

    const int s0 = ssrc[i0];
    const int s1 = v1 ? ssrc[i1] : s0;
    const int s2 = v2 ? ssrc[i2] : s0;
    const int s3 = v3 ? ssrc[i3] : s0;

    const float2 ww0 = ew[i0];
    const float2 ww1 = v1 ? ew[i1] : make_float2(0.f, 0.f);
    const float2 ww2 = v2 ? ew[i2] : make_float2(0.f, 0.f);
    const float2 ww3 = v3 ? ew[i3] : make_float2(0.f, 0.f);

    const ushort4 g0 = *(const ushort4*)(h + (size_t)s0 * 128 + c * 4);
    const ushort4 g1 = *(const ushort4*)(h + (size_t)s1 * 128 + c * 4);
    const ushort4 g2 = *(const ushort4*)(h + (size_t)s2 * 128 + c * 4);
    const ushort4 g3 = *(const ushort4*)(h + (size_t)s3 * 128 + c * 4);

    const float w0 = head ? ww0.y : ww0.x;
    const float w1 = head ? ww1.y : ww1.x;
    const float w2 = head ? ww2.y : ww2.x;
    const float w3 = head ? ww3.y : ww3.x;

    den += (w0 + w1) + (w2 + w3);
    a.x += w0 * bf2f(g0.x) + w1 * bf2f(g1.x) + w2 * bf2f(g2.x) + w3 * bf2f(g3.x);
    a.y += w0 * bf2f(g0.y) + w1 * bf2f(g1.y) + w2 * bf2f(g2.y) + w3 * bf2f(g3.y);
    a.z += w0 * bf2f(g0.z) + w1 * bf2f(g1.z) + w2 * bf2f(g2.z) + w3 * bf2f(g3.z);
    a.w += w0 * bf2f(g0.w) + w1 * bf2f(g1.w) + w2 * bf2f(g2.w) + w3 * bf2f(g3.w);
  }

  if (half == 0) {  // self-loop
    const float2 asv = *(const float2*)(asrc + 2 * n);
    const float2 adv = *(const float2*)(adst + 2 * n);
    float e = head ? (asv.y + adv.y) : (asv.x + adv.x);
    e = e > 0.f ? e : NEG * e;
    const float w = __expf(e);
    den += w;
    const ushort4 g = *(const ushort4*)(h + (size_t)n * 128 + c * 4);
    a.x += w * bf2f(g.x); a.y += w * bf2f(g.y);
    a.z += w * bf2f(g.z); a.w += w * bf2f(g.w);
  }

  a.x += __shfl_xor(a.x, 32, 64);
  a.y += __shfl_xor(a.y, 32, 64);
  a.z += __shfl_xor(a.z, 32, 64);
  a.w += __shfl_xor(a.w, 32, 64);
  den += __shfl_xor(den, 32, 64);

  if (half == 0) {
    const float4 bv = *(const float4*)(b + c * 4);
    const float inv = 1.f / den;
    float4 r;
    r.x = a.x * inv + bv.x;
    r.y = a.y * inv + bv.y;
    r.z = a.z * inv + bv.z;
    r.w = a.w * inv + bv.w;
    r.x = r.x > 0.f ? r.x : 0.f;
    r.y = r.y > 0.f ? r.y : 0.f;
    r.z = r.z > 0.f ? r.z : 0.f;
    r.w = r.w > 0.f ? r.w : 0.f;
    *(float4*)(out + (size_t)n * 128 + c * 4) = r;
  }
}

// ===========================================================================
// Layer-2 segment aggregation (unchanged, h2 fp32)
// ===========================================================================
__global__ __launch_bounds__(256) void agg2_kernel(
    const int* __restrict__ offs, const int* __restrict__ ssrc,
    const float* __restrict__ ew,
    const float* __restrict__ h, const float* __restrict__ asrc,
    const float* __restrict__ adst, const float* __restrict__ b,
    float* __restrict__ out, int N)
{
  const int n = (blockIdx.x * 256 + threadIdx.x) >> 6;
  const int lane = threadIdx.x & 63;
  const int g = lane >> 3;
  const int c4 = (lane & 7) << 2;
  if (n >= N) return;

  float4 a = make_float4(0.f, 0.f, 0.f, 0.f);
  float den = 0.f;

  const int beg = offs[n];
  const int end = offs[n + 1];

  for (int i0 = beg + g; i0 < end; i0 += 16) {
    const int i1 = i0 + 8;
    const bool v1 = i1 < end;

    const int s0 = ssrc[i0];
    const int s1 = v1 ? ssrc[i1] : s0;
    const float w0 = ew[i0];
    const float w1 = v1 ? ew[i1] : 0.f;

    const float4 h0 = *(const float4*)(h + (size_t)s0 * 32 + c4);
    const float4 h1 = *(const float4*)(h + (size_t)s1 * 32 + c4);

    den += w0 + w1;
    a.x += w0 * h0.x + w1 * h1.x;
    a.y += w0 * h0.y + w1 * h1.y;
    a.z += w0 * h0.z + w1 * h1.z;
    a.w += w0 * h0.w + w1 * h1.w;
  }

  if (g == 0) {  // self-loop
    float e = asrc[n] + adst[n];
    e = e > 0.f ? e : NEG * e;
    const float w = __expf(e);
    den += w;
    const float4 hv = *(const float4*)(h + (size_t)n * 32 + c4);
    a.x += w * hv.x; a.y += w * hv.y; a.z += w * hv.z; a.w += w * hv.w;
  }

#pragma unroll
  for (int m = 8; m <= 32; m <<= 1) {
    a.x += __shfl_xor(a.x, m, 64);
    a.y += __shfl_xor(a.y, m, 64);
    a.z += __shfl_xor(a.z, m, 64);
    a.w += __shfl_xor(a.w, m, 64);
    den += __shfl_xor(den, m, 64);
  }

  if (g == 0) {
    const float4 bv = *(const float4*)(b + c4);
    const float inv = 1.f / den;
    float4 r;
    r.x = a.x * inv + bv.x;
    r.y = a.y * inv + bv.y;
    r.z = a.z * inv + bv.z;
    r.w = a.w * inv + bv.w;
    *(float4*)(out + (size_t)n * 32 + c4) = r;
  }
}

// ===========================================================================
extern "C" void kernel_launch(void* const* d_in, const int* in_sizes, int n_in,
                              void* d_out, int out_size, void* d_ws, size_t ws_size,
                              hipStream_t stream)
{
  const float* x   = (const float*)d_in[0];
  const int*   ei  = (const int*)  d_in[1];
  const float* W1  = (const float*)d_in[2];
  const float* as1 = (const float*)d_in[3];
  const float* ad1 = (const float*)d_in[4];
  const float* b1  = (const float*)d_in[5];
  const float* W2  = (const float*)d_in[6];
  const float* as2 = (const float*)d_in[7];
  const float* ad2 = (const float*)d_in[8];
  const float* b2  = (const float*)d_in[9];

  const int N = in_sizes[0] / 128;
  const int E = in_sizes[1] / 2;

  // workspace layout
  char* p = (char*)d_ws;
  int* counts  = (int*)p;                p += (size_t)N * 4;
  int* cursor  = (int*)p;                p += (size_t)N * 4;
  int* offs    = (int*)p;                p += (size_t)(N + 1) * 4;
  int* partial = (int*)p;                p += (size_t)SCAN_BLOCKS * 4;
  int* ssrc    = (int*)p;                p += (size_t)E * 4;
  int* sdst    = (int*)p;                p += (size_t)E * 4;
  float2* ew1  = (float2*)p;             p += (size_t)E * 8;
  float* ew2   = (float*)p;              p += (size_t)E * 4;
  ushort* h1   = (ushort*)p;             p += (size_t)N * 128 * 2;
  float* out1  = (float*)p;              p += (size_t)N * 128 * 4;
  float* asrc1 = (float*)p;              p += (size_t)N * 2 * 4;
  float* adst1 = (float*)p;              p += (size_t)N * 2 * 4;
  float* h2    = (float*)p;              p += (size_t)N * 32 * 4;
  float* asrc2 = (float*)p;              p += (size_t)N * 4;
  float* adst2 = (float*)p;              p += (size_t)N * 4;
  float* out   = (float*)d_out;          // N*32

  // ---- Phase A: dst-sorted CSR ----
  hipMemsetAsync(counts, 0, (size_t)N * 4, stream);
  hist_kernel<<<(E + 255) / 256, 256, 0, stream>>>(ei, counts, E);
  scan_a<<<SCAN_BLOCKS, 256, 0, stream>>>(counts, partial, N);
  scan_c<<<SCAN_BLOCKS, 256, 0, stream>>>(counts, partial, offs, cursor, N);
  scatter_kernel<<<(E + 255) / 256, 256, 0, stream>>>(ei, cursor, ssrc, sdst, E);

  // ---- layer 1 ----
  gemm1_kernel<<<(N + BM1 - 1) / BM1, 256, 0, stream>>>(x, W1, as1, ad1,
                                                        h1, asrc1, adst1, N);
  edgew1_kernel<<<(E + 255) / 256, 256, 0, stream>>>(ssrc, sdst, asrc1, adst1, ew1, E);
  agg1_kernel<<<(N * 64 + 255) / 256, 256, 0, stream>>>(offs, ssrc, ew1, h1,
                                                        asrc1, adst1, b1, out1, N);

  // ---- layer 2 ----
  gemm2_kernel<<<(N + BM2 - 1) / BM2, 256, 0, stream>>>(out1, W2, as2, ad2,
                                                        h2, asrc2, adst2, N);
  edgew2_kernel<<<(E + 255) / 256, 256, 0, stream>>>(ssrc, sdst, asrc2, adst2, ew2, E);
  agg2_kernel<<<(N * 64 + 255) / 256, 256, 0, stream>>>(offs, ssrc, ew2, h2,
                                                        asrc2, adst2, b2, out, N);
}

// Round 9
// 243.050 us; speedup vs baseline: 1.5122x; 1.2732x over previous
//
#include <hip/hip_runtime.h>

#define NEG 0.2f

constexpr int SCAN_BLOCKS = 64;

// bf16 helpers (RNE convert; bf16->f32 is exact via bit shift)
__device__ __forceinline__ ushort f2bf(float f) {
  uint u = __float_as_uint(f);
  return (ushort)((u + 0x7fffu + ((u >> 16) & 1u)) >> 16);
}
__device__ __forceinline__ float bf2f(ushort v) {
  return __uint_as_float((uint)v << 16);
}

// ===========================================================================
// Phase A: build dst-sorted CSR (shared by both GAT layers)
// ===========================================================================
__global__ void hist_kernel(const int* __restrict__ ei, int* __restrict__ counts, int E)
{
  const int i = blockIdx.x * 256 + threadIdx.x;
  if (i < E) atomicAdd(&counts[ei[E + i]], 1);
}

__global__ __launch_bounds__(256) void scan_a(const int* __restrict__ counts,
                                              int* __restrict__ partial, int N)
{
  const int b = blockIdx.x, t = threadIdx.x;
  const int per_block = (N + SCAN_BLOCKS - 1) / SCAN_BLOCKS;
  const int beg = b * per_block;
  const int end = min(beg + per_block, N);
  int s = 0;
  for (int i = beg + t; i < end; i += 256) s += counts[i];
#pragma unroll
  for (int m = 32; m >= 1; m >>= 1) s += __shfl_xor(s, m, 64);
  __shared__ int ws[4];
  if ((t & 63) == 0) ws[t >> 6] = s;
  __syncthreads();
  if (t == 0) partial[b] = ws[0] + ws[1] + ws[2] + ws[3];
}

__global__ __launch_bounds__(256) void scan_c(const int* __restrict__ counts,
                                              const int* __restrict__ partial,
                                              int* __restrict__ offs,
                                              int* __restrict__ cursor, int N)
{
  const int b = blockIdx.x, t = threadIdx.x;
  const int per_block = (N + SCAN_BLOCKS - 1) / SCAN_BLOCKS;
  const int per_thread = (per_block + 255) / 256;
  const int beg = b * per_block;
  const int end = min(beg + per_block, N);

  int base = 0;
  for (int i = 0; i < SCAN_BLOCKS; ++i)
    if (i < b) base += partial[i];

  const int tbeg = beg + t * per_thread;
  const int tend = min(tbeg + per_thread, end);
  int tsum = 0;
  for (int i = tbeg; i < tend; ++i) tsum += counts[i];

  __shared__ int sums[256];
  sums[t] = tsum;
  __syncthreads();
  for (int off = 1; off < 256; off <<= 1) {
    int v = (t >= off) ? sums[t - off] : 0;
    __syncthreads();
    if (t >= off) sums[t] += v;
    __syncthreads();
  }
  int run = base + (t ? sums[t - 1] : 0);
  for (int i = tbeg; i < tend; ++i) {
    offs[i] = run;
    cursor[i] = run;
    run += counts[i];
  }
  if (b == SCAN_BLOCKS - 1 && t == 255) offs[N] = base + sums[255];
}

__global__ void scatter_kernel(const int* __restrict__ ei, int* __restrict__ cursor,
                               int* __restrict__ ssrc, int* __restrict__ sdst, int E)
{
  const int i = blockIdx.x * 256 + threadIdx.x;
  if (i < E) {
    const int d = ei[E + i];
    const int pos = atomicAdd(&cursor[d], 1);
    ssrc[pos] = ei[i];
    sdst[pos] = d;
  }
}

// ===========================================================================
// Edge-parallel softmax-weight precompute
// ===========================================================================
__global__ void edgew1_kernel(const int* __restrict__ ssrc, const int* __restrict__ sdst,
                              const float* __restrict__ asrc, const float* __restrict__ adst,
                              float2* __restrict__ ew, int E)
{
  const int i = blockIdx.x * 256 + threadIdx.x;
  if (i >= E) return;
  const int s = ssrc[i], d = sdst[i];
  const float2 av = *(const float2*)(asrc + 2 * s);
  const float2 dv = *(const float2*)(adst + 2 * d);
  float e0 = av.x + dv.x, e1 = av.y + dv.y;
  e0 = e0 > 0.f ? e0 : NEG * e0;
  e1 = e1 > 0.f ? e1 : NEG * e1;
  ew[i] = make_float2(__expf(e0), __expf(e1));
}

__global__ void edgew2_kernel(const int* __restrict__ ssrc, const int* __restrict__ sdst,
                              const float* __restrict__ asrc, const float* __restrict__ adst,
                              float* __restrict__ ew, int E)
{
  const int i = blockIdx.x * 256 + threadIdx.x;
  if (i >= E) return;
  float e = asrc[ssrc[i]] + adst[sdst[i]];
  e = e > 0.f ? e : NEG * e;
  ew[i] = __expf(e);
}

// ===========================================================================
// GEMM1: h1 = x @ W1  (N x 128)@(128 x 128). x-tile in LDS; W direct from
// global (L2-resident). k-step 2 to keep live regs < 64 (NO spill — round 8
// showed hipcc pins VGPR=64 when LDS is used and spills bigger live sets).
// h1 stored bf16; alphas fp32.
// ===========================================================================
constexpr int BM1 = 32;

__global__ __launch_bounds__(256, 4) void gemm1_kernel(
    const float* __restrict__ x, const float* __restrict__ W,
    const float* __restrict__ a_src, const float* __restrict__ a_dst,
    ushort* __restrict__ h, float* __restrict__ asrc, float* __restrict__ adst,
    int N)
{
  __shared__ float xs[BM1][132];   // +4 pad
  const int t = threadIdx.x;
  const int n0 = blockIdx.x * BM1;

  // stage x tile (32x128, coalesced float4)
#pragma unroll
  for (int i = 0; i < 4; ++i) {
    const int idx = t + i * 256;
    const int row = idx >> 5;
    const int cq  = idx & 31;
    int rn = n0 + row; if (rn >= N) rn = N - 1;
    *(float4*)&xs[row][cq * 4] = *(const float4*)(x + (size_t)rn * 128 + cq * 4);
  }
  __syncthreads();

  const int c4 = (t & 31) << 2;        // cols c4..c4+3
  const int tn = (t >> 5) << 2;        // first of 4 local nodes

  float4 acc[4];
#pragma unroll
  for (int j = 0; j < 4; ++j) acc[j] = make_float4(0.f, 0.f, 0.f, 0.f);

#pragma unroll 2
  for (int k0 = 0; k0 < 128; k0 += 2) {
    const float4 w0 = *(const float4*)(W + (size_t)(k0 + 0) * 128 + c4);
    const float4 w1 = *(const float4*)(W + (size_t)(k0 + 1) * 128 + c4);
#pragma unroll
    for (int j = 0; j < 4; ++j) {
      const float2 xv = *(const float2*)&xs[tn + j][k0];
      acc[j].x += xv.x * w0.x + xv.y * w1.x;
      acc[j].y += xv.x * w0.y + xv.y * w1.y;
      acc[j].z += xv.x * w0.z + xv.y * w1.z;
      acc[j].w += xv.x * w0.w + xv.y * w1.w;
    }
  }

  const float4 avs = *(const float4*)(a_src + c4);
  const float4 avd = *(const float4*)(a_dst + c4);
  const int head = (t >> 4) & 1;

#pragma unroll
  for (int j = 0; j < 4; ++j) {
    const int nn = n0 + tn + j;
    if (nn >= N) break;
    ushort4 hv;
    hv.x = f2bf(acc[j].x); hv.y = f2bf(acc[j].y);
    hv.z = f2bf(acc[j].z); hv.w = f2bf(acc[j].w);
    *(ushort4*)(h + (size_t)nn * 128 + c4) = hv;
    float vs = acc[j].x * avs.x + acc[j].y * avs.y + acc[j].z * avs.z + acc[j].w * avs.w;
    float vd = acc[j].x * avd.x + acc[j].y * avd.y + acc[j].z * avd.z + acc[j].w * avd.w;
#pragma unroll
    for (int m = 1; m <= 8; m <<= 1) {
      vs += __shfl_xor(vs, m, 64);
      vd += __shfl_xor(vd, m, 64);
    }
    if ((t & 15) == 0) {
      asrc[nn * 2 + head] = vs;
      adst[nn * 2 + head] = vd;
    }
  }
}

// ===========================================================================
// GEMM2: h2 = out1 @ W2  (N x 128)@(128 x 32). x-tile + W2 in LDS.
// ===========================================================================
constexpr int BM2 = 32;

__global__ __launch_bounds__(256, 4) void gemm2_kernel(
    const float* __restrict__ x, const float* __restrict__ W,
    const float* __restrict__ a_src, const float* __restrict__ a_dst,
    float* __restrict__ h, float* __restrict__ asrc, float* __restrict__ adst,
    int N)
{
  __shared__ float xs[BM2][132];
  __shared__ float wsm[128][32];
  const int t = threadIdx.x;
  const int n0 = blockIdx.x * BM2;

#pragma unroll
  for (int i = 0; i < 4; ++i) {
    const int idx = t + i * 256;
    const int row = idx >> 5;
    const int cq  = idx & 31;
    int rn = n0 + row; if (rn >= N) rn = N - 1;
    *(float4*)&xs[row][cq * 4] = *(const float4*)(x + (size_t)rn * 128 + cq * 4);
  }
#pragma unroll
  for (int i = 0; i < 4; ++i) {
    const int idx = t + i * 256;       // float4 slot 0..1023
    const int row = idx >> 3;          // k row 0..127
    const int cq  = idx & 7;           // col quad 0..7
    *(float4*)&wsm[row][cq * 4] = *(const float4*)(W + row * 32 + cq * 4);
  }
  __syncthreads();

  const int c4 = (t & 7) << 2;
  const int tn = t >> 3;

  float4 acc = make_float4(0.f, 0.f, 0.f, 0.f);

#pragma unroll 4
  for (int k0 = 0; k0 < 128; k0 += 4) {
    const float4 w0 = *(const float4*)&wsm[k0 + 0][c4];
    const float4 w1 = *(const float4*)&wsm[k0 + 1][c4];
    const float4 w2 = *(const float4*)&wsm[k0 + 2][c4];
    const float4 w3 = *(const float4*)&wsm[k0 + 3][c4];
    const float4 xv = *(const float4*)&xs[tn][k0];
    acc.x += xv.x * w0.x + xv.y * w1.x + xv.z * w2.x + xv.w * w3.x;
    acc.y += xv.x * w0.y + xv.y * w1.y + xv.z * w2.y + xv.w * w3.y;
    acc.z += xv.x * w0.z + xv.y * w1.z + xv.z * w2.z + xv.w * w3.z;
    acc.w += xv.x * w0.w + xv.y * w1.w + xv.z * w2.w + xv.w * w3.w;
  }

  const int nn = n0 + tn;
  if (nn < N) {
    *(float4*)(h + (size_t)nn * 32 + c4) = acc;

    const float4 avs = *(const float4*)(a_src + c4);
    const float4 avd = *(const float4*)(a_dst + c4);
    float vs = acc.x * avs.x + acc.y * avs.y + acc.z * avs.z + acc.w * avs.w;
    float vd = acc.x * avd.x + acc.y * avd.y + acc.z * avd.z + acc.w * avd.w;
#pragma unroll
    for (int m = 1; m <= 4; m <<= 1) {
      vs += __shfl_xor(vs, m, 64);
      vd += __shfl_xor(vd, m, 64);
    }
    if ((t & 7) == 0) {
      asrc[nn] = vs;
      adst[nn] = vd;
    }
  }
}

// ===========================================================================
// Layer-1 segment aggregation: h1 is bf16 (half the gather bytes).
// ===========================================================================
__global__ __launch_bounds__(256) void agg1_kernel(
    const int* __restrict__ offs, const int* __restrict__ ssrc,
    const float2* __restrict__ ew,
    const ushort* __restrict__ h, const float* __restrict__ asrc,
    const float* __restrict__ adst, const float* __restrict__ b,
    float* __restrict__ out, int N)
{
  const int n = (blockIdx.x * 256 + threadIdx.x) >> 6;
  const int lane = threadIdx.x & 63;
  const int c = lane & 31;
  const int half = lane >> 5;
  const int head = c >> 4;
  if (n >= N) return;

  float4 a = make_float4(0.f, 0.f, 0.f, 0.f);
  float den = 0.f;

  const int beg = offs[n];
  const int end = offs[n + 1];

  for (int i0 = beg + half; i0 < end; i0 += 8) {
    const int i1 = i0 + 2, i2 = i0 + 4, i3 = i0 + 6;
    const bool v1 = i1 < end, v2 = i2 < end, v3 = i3 < end;

    const int s0 = ssrc[i0];
    const int s1 = v1 ? ssrc[i1] : s0;
    const int s2 = v2 ? ssrc[i2] : s0;
    const int s3 = v3 ? ssrc[i3] : s0;

    const float2 ww0 = ew[i0];
    const float2 ww1 = v1 ? ew[i1] : make_float2(0.f, 0.f);
    const float2 ww2 = v2 ? ew[i2] : make_float2(0.f, 0.f);
    const float2 ww3 = v3 ? ew[i3] : make_float2(0.f, 0.f);

    const ushort4 g0 = *(const ushort4*)(h + (size_t)s0 * 128 + c * 4);
    const ushort4 g1 = *(const ushort4*)(h + (size_t)s1 * 128 + c * 4);
    const ushort4 g2 = *(const ushort4*)(h + (size_t)s2 * 128 + c * 4);
    const ushort4 g3 = *(const ushort4*)(h + (size_t)s3 * 128 + c * 4);

    const float w0 = head ? ww0.y : ww0.x;
    const float w1 = head ? ww1.y : ww1.x;
    const float w2 = head ? ww2.y : ww2.x;
    const float w3 = head ? ww3.y : ww3.x;

    den += (w0 + w1) + (w2 + w3);
    a.x += w0 * bf2f(g0.x) + w1 * bf2f(g1.x) + w2 * bf2f(g2.x) + w3 * bf2f(g3.x);
    a.y += w0 * bf2f(g0.y) + w1 * bf2f(g1.y) + w2 * bf2f(g2.y) + w3 * bf2f(g3.y);
    a.z += w0 * bf2f(g0.z) + w1 * bf2f(g1.z) + w2 * bf2f(g2.z) + w3 * bf2f(g3.z);
    a.w += w0 * bf2f(g0.w) + w1 * bf2f(g1.w) + w2 * bf2f(g2.w) + w3 * bf2f(g3.w);
  }

  if (half == 0) {  // self-loop
    const float2 asv = *(const float2*)(asrc + 2 * n);
    const float2 adv = *(const float2*)(adst + 2 * n);
    float e = head ? (asv.y + adv.y) : (asv.x + adv.x);
    e = e > 0.f ? e : NEG * e;
    const float w = __expf(e);
    den += w;
    const ushort4 g = *(const ushort4*)(h + (size_t)n * 128 + c * 4);
    a.x += w * bf2f(g.x); a.y += w * bf2f(g.y);
    a.z += w * bf2f(g.z); a.w += w * bf2f(g.w);
  }

  a.x += __shfl_xor(a.x, 32, 64);
  a.y += __shfl_xor(a.y, 32, 64);
  a.z += __shfl_xor(a.z, 32, 64);
  a.w += __shfl_xor(a.w, 32, 64);
  den += __shfl_xor(den, 32, 64);

  if (half == 0) {
    const float4 bv = *(const float4*)(b + c * 4);
    const float inv = 1.f / den;
    float4 r;
    r.x = a.x * inv + bv.x;
    r.y = a.y * inv + bv.y;
    r.z = a.z * inv + bv.z;
    r.w = a.w * inv + bv.w;
    r.x = r.x > 0.f ? r.x : 0.f;
    r.y = r.y > 0.f ? r.y : 0.f;
    r.z = r.z > 0.f ? r.z : 0.f;
    r.w = r.w > 0.f ? r.w : 0.f;
    *(float4*)(out + (size_t)n * 128 + c * 4) = r;
  }
}

// ===========================================================================
// Layer-2 segment aggregation (unchanged, h2 fp32)
// ===========================================================================
__global__ __launch_bounds__(256) void agg2_kernel(
    const int* __restrict__ offs, const int* __restrict__ ssrc,
    const float* __restrict__ ew,
    const float* __restrict__ h, const float* __restrict__ asrc,
    const float* __restrict__ adst, const float* __restrict__ b,
    float* __restrict__ out, int N)
{
  const int n = (blockIdx.x * 256 + threadIdx.x) >> 6;
  const int lane = threadIdx.x & 63;
  const int g = lane >> 3;
  const int c4 = (lane & 7) << 2;
  if (n >= N) return;

  float4 a = make_float4(0.f, 0.f, 0.f, 0.f);
  float den = 0.f;

  const int beg = offs[n];
  const int end = offs[n + 1];

  for (int i0 = beg + g; i0 < end; i0 += 16) {
    const int i1 = i0 + 8;
    const bool v1 = i1 < end;

    const int s0 = ssrc[i0];
    const int s1 = v1 ? ssrc[i1] : s0;
    const float w0 = ew[i0];
    const float w1 = v1 ? ew[i1] : 0.f;

    const float4 h0 = *(const float4*)(h + (size_t)s0 * 32 + c4);
    const float4 h1 = *(const float4*)(h + (size_t)s1 * 32 + c4);

    den += w0 + w1;
    a.x += w0 * h0.x + w1 * h1.x;
    a.y += w0 * h0.y + w1 * h1.y;
    a.z += w0 * h0.z + w1 * h1.z;
    a.w += w0 * h0.w + w1 * h1.w;
  }

  if (g == 0) {  // self-loop
    float e = asrc[n] + adst[n];
    e = e > 0.f ? e : NEG * e;
    const float w = __expf(e);
    den += w;
    const float4 hv = *(const float4*)(h + (size_t)n * 32 + c4);
    a.x += w * hv.x; a.y += w * hv.y; a.z += w * hv.z; a.w += w * hv.w;
  }

#pragma unroll
  for (int m = 8; m <= 32; m <<= 1) {
    a.x += __shfl_xor(a.x, m, 64);
    a.y += __shfl_xor(a.y, m, 64);
    a.z += __shfl_xor(a.z, m, 64);
    a.w += __shfl_xor(a.w, m, 64);
    den += __shfl_xor(den, m, 64);
  }

  if (g == 0) {
    const float4 bv = *(const float4*)(b + c4);
    const float inv = 1.f / den;
    float4 r;
    r.x = a.x * inv + bv.x;
    r.y = a.y * inv + bv.y;
    r.z = a.z * inv + bv.z;
    r.w = a.w * inv + bv.w;
    *(float4*)(out + (size_t)n * 32 + c4) = r;
  }
}

// ===========================================================================
extern "C" void kernel_launch(void* const* d_in, const int* in_sizes, int n_in,
                              void* d_out, int out_size, void* d_ws, size_t ws_size,
                              hipStream_t stream)
{
  const float* x   = (const float*)d_in[0];
  const int*   ei  = (const int*)  d_in[1];
  const float* W1  = (const float*)d_in[2];
  const float* as1 = (const float*)d_in[3];
  const float* ad1 = (const float*)d_in[4];
  const float* b1  = (const float*)d_in[5];
  const float* W2  = (const float*)d_in[6];
  const float* as2 = (const float*)d_in[7];
  const float* ad2 = (const float*)d_in[8];
  const float* b2  = (const float*)d_in[9];

  const int N = in_sizes[0] / 128;
  const int E = in_sizes[1] / 2;

  // workspace layout
  char* p = (char*)d_ws;
  int* counts  = (int*)p;                p += (size_t)N * 4;
  int* cursor  = (int*)p;                p += (size_t)N * 4;
  int* offs    = (int*)p;                p += (size_t)(N + 1) * 4;
  int* partial = (int*)p;                p += (size_t)SCAN_BLOCKS * 4;
  int* ssrc    = (int*)p;                p += (size_t)E * 4;
  int* sdst    = (int*)p;                p += (size_t)E * 4;
  float2* ew1  = (float2*)p;             p += (size_t)E * 8;
  float* ew2   = (float*)p;              p += (size_t)E * 4;
  ushort* h1   = (ushort*)p;             p += (size_t)N * 128 * 2;
  float* out1  = (float*)p;              p += (size_t)N * 128 * 4;
  float* asrc1 = (float*)p;              p += (size_t)N * 2 * 4;
  float* adst1 = (float*)p;              p += (size_t)N * 2 * 4;
  float* h2    = (float*)p;              p += (size_t)N * 32 * 4;
  float* asrc2 = (float*)p;              p += (size_t)N * 4;
  float* adst2 = (float*)p;              p += (size_t)N * 4;
  float* out   = (float*)d_out;          // N*32

  // ---- Phase A: dst-sorted CSR ----
  hipMemsetAsync(counts, 0, (size_t)N * 4, stream);
  hist_kernel<<<(E + 255) / 256, 256, 0, stream>>>(ei, counts, E);
  scan_a<<<SCAN_BLOCKS, 256, 0, stream>>>(counts, partial, N);
  scan_c<<<SCAN_BLOCKS, 256, 0, stream>>>(counts, partial, offs, cursor, N);
  scatter_kernel<<<(E + 255) / 256, 256, 0, stream>>>(ei, cursor, ssrc, sdst, E);

  // ---- layer 1 ----
  gemm1_kernel<<<(N + BM1 - 1) / BM1, 256, 0, stream>>>(x, W1, as1, ad1,
                                                        h1, asrc1, adst1, N);
  edgew1_kernel<<<(E + 255) / 256, 256, 0, stream>>>(ssrc, sdst, asrc1, adst1, ew1, E);
  agg1_kernel<<<(N * 64 + 255) / 256, 256, 0, stream>>>(offs, ssrc, ew1, h1,
                                                        asrc1, adst1, b1, out1, N);

  // ---- layer 2 ----
  gemm2_kernel<<<(N + BM2 - 1) / BM2, 256, 0, stream>>>(out1, W2, as2, ad2,
                                                        h2, asrc2, adst2, N);
  edgew2_kernel<<<(E + 255) / 256, 256, 0, stream>>>(ssrc, sdst, asrc2, adst2, ew2, E);
  agg2_kernel<<<(N * 64 + 255) / 256, 256, 0, stream>>>(offs, ssrc, ew2, h2,
                                                        asrc2, adst2, b2, out, N);
}